// Round 1
// baseline (1095.040 us; speedup 1.0000x reference)
//
#include <hip/hip_runtime.h>

#define F 128
#define NGRAPH 512

// ---------------- CSR build ----------------

__global__ void k_zero(int* __restrict__ counts, int* __restrict__ gstart, int n, int ngp1) {
    int i = blockIdx.x * blockDim.x + threadIdx.x;
    if (i < n) counts[i] = 0;
    if (i < ngp1) gstart[i] = n;   // sentinel = n
}

__global__ void k_hist(const int* __restrict__ dst, int* __restrict__ counts, int e) {
    for (int i = blockIdx.x * blockDim.x + threadIdx.x; i < e; i += gridDim.x * blockDim.x)
        atomicAdd(&counts[dst[i]], 1);
}

__global__ void k_scan(const int* __restrict__ counts, int* __restrict__ rs,
                       int* __restrict__ cursor, int n) {
    __shared__ int lsum[1024];
    const int t = threadIdx.x;
    const int npt = (n + 1023) >> 10;
    const int base = t * npt;
    int s = 0;
    for (int i = 0; i < npt; i++) { int idx = base + i; if (idx < n) s += counts[idx]; }
    lsum[t] = s;
    __syncthreads();
    for (int off = 1; off < 1024; off <<= 1) {
        int v = (t >= off) ? lsum[t - off] : 0;
        __syncthreads();
        lsum[t] += v;
        __syncthreads();
    }
    int run = (t == 0) ? 0 : lsum[t - 1];
    for (int i = 0; i < npt; i++) {
        int idx = base + i;
        if (idx < n) { rs[idx] = run; cursor[idx] = run; run += counts[idx]; }
    }
    if (t == 1023) rs[n] = run;
}

__global__ void k_scatter(const int* __restrict__ src, const int* __restrict__ dst,
                          int* __restrict__ cursor, int* __restrict__ csr, int e) {
    for (int i = blockIdx.x * blockDim.x + threadIdx.x; i < e; i += gridDim.x * blockDim.x) {
        int p = atomicAdd(&cursor[dst[i]], 1);
        csr[p] = src[i];
    }
}

__global__ void k_bounds(const int* __restrict__ batch, int* __restrict__ gstart, int n) {
    int i = blockIdx.x * blockDim.x + threadIdx.x;
    if (i < n) atomicMin(&gstart[batch[i]], i);
}

__global__ void k_fixb(int* __restrict__ gstart, int ng, int n) {
    if (blockIdx.x == 0 && threadIdx.x == 0) {
        gstart[ng] = n;
        for (int g = ng - 1; g >= 0; g--)
            if (gstart[g] > gstart[g + 1]) gstart[g] = gstart[g + 1];
    }
}

// ---------------- dual GEMM: hl = h@Wl, hr = h@Wr + b ----------------
// block = 256 threads, 64 rows/block. Thread (cg,rg): 4 cols x 8 rows, both mats.

__global__ __launch_bounds__(256) void k_gemm_dual(
    const float* __restrict__ h, const float* __restrict__ Wl,
    const float* __restrict__ Wr, const float* __restrict__ bias,
    float* __restrict__ hl, float* __restrict__ hr, int nrows)
{
    __shared__ float xs[64][F];
    const int t = threadIdx.x;
    const int row0 = blockIdx.x * 64;
    {
        const int nv = 64 * F / 4;  // 2048 float4
        const float4* srcp = (const float4*)(h + (size_t)row0 * F);
        float4* dl = (float4*)&xs[0][0];
        for (int i = t; i < nv; i += 256) {
            int r = i >> 5;  // 32 float4 per row
            float4 v;
            if (row0 + r < nrows) v = srcp[i];
            else v = make_float4(0.f, 0.f, 0.f, 0.f);
            dl[i] = v;
        }
    }
    __syncthreads();
    const int cg = t & 31, rg = t >> 5;
    const int c0 = cg * 4, r0 = rg * 8;
    float accl[8][4] = {};
    float accr[8][4] = {};
#pragma unroll 2
    for (int k = 0; k < F; k++) {
        const float4 wl = *(const float4*)&Wl[k * F + c0];
        const float4 wr = *(const float4*)&Wr[k * F + c0];
#pragma unroll
        for (int r = 0; r < 8; r++) {
            const float xv = xs[r0 + r][k];
            accl[r][0] = fmaf(xv, wl.x, accl[r][0]);
            accl[r][1] = fmaf(xv, wl.y, accl[r][1]);
            accl[r][2] = fmaf(xv, wl.z, accl[r][2]);
            accl[r][3] = fmaf(xv, wl.w, accl[r][3]);
            accr[r][0] = fmaf(xv, wr.x, accr[r][0]);
            accr[r][1] = fmaf(xv, wr.y, accr[r][1]);
            accr[r][2] = fmaf(xv, wr.z, accr[r][2]);
            accr[r][3] = fmaf(xv, wr.w, accr[r][3]);
        }
    }
    const float4 bv = *(const float4*)&bias[c0];
#pragma unroll
    for (int r = 0; r < 8; r++) {
        int row = row0 + r0 + r;
        if (row < nrows) {
            float4 vl = make_float4(accl[r][0], accl[r][1], accl[r][2], accl[r][3]);
            float4 vr = make_float4(accr[r][0] + bv.x, accr[r][1] + bv.y,
                                    accr[r][2] + bv.z, accr[r][3] + bv.w);
            *(float4*)&hl[(size_t)row * F + c0] = vl;
            *(float4*)&hr[(size_t)row * F + c0] = vr;
        }
    }
}

// ---------------- aggregation: out[v] = relu(sum_e hl[src[e]]/deg + hr[v]) ----------------
// 2 nodes/block, 128 threads per node (one per channel).

template <int RELU, int HASR>
__global__ void k_agg(const float* __restrict__ hl, const float* __restrict__ hr,
                      const int* __restrict__ rs, const int* __restrict__ csr,
                      float* __restrict__ out, int nnodes)
{
    int v = blockIdx.x * 2 + (threadIdx.x >> 7);
    if (v >= nnodes) return;
    int c = threadIdx.x & 127;
    int e0 = rs[v], e1 = rs[v + 1];
    float s = 0.f;
    for (int e = e0; e < e1; e++) {
        int sn = csr[e];
        s += hl[(size_t)sn * F + c];
    }
    float o = s / (float)max(e1 - e0, 1);
    if (HASR) o += hr[(size_t)v * F + c];
    if (RELU) o = fmaxf(o, 0.f);
    out[(size_t)v * F + c] = o;
}

// ---------------- per-graph mean pool of t (=agg4) and h3 ----------------

__global__ void k_pool(const float* __restrict__ tagg, const float* __restrict__ h3,
                       const int* __restrict__ gstart,
                       float* __restrict__ ps1, float* __restrict__ ps2)
{
    int g = blockIdx.x, c = threadIdx.x;  // 128 threads
    int v0 = gstart[g], v1 = gstart[g + 1];
    float s1 = 0.f, s2 = 0.f;
    for (int v = v0; v < v1; v++) {
        s1 += tagg[(size_t)v * F + c];
        s2 += h3[(size_t)v * F + c];
    }
    float inv = 1.f / (float)max(v1 - v0, 1);
    ps1[g * F + c] = s1 * inv;
    ps2[g * F + c] = s2 * inv;
}

// ---------------- final tiny GEMM: out = ps1@W4l + ps2@W4r + b4 ----------------
// one wave per graph

__global__ void k_final(const float* __restrict__ ps1, const float* __restrict__ ps2,
                        const float* __restrict__ W4l, const float* __restrict__ W4r,
                        const float* __restrict__ b4, float* __restrict__ out, int ngraph)
{
    int g = blockIdx.x * 4 + (threadIdx.x >> 6);
    int lane = threadIdx.x & 63;
    if (g >= ngraph) return;
    int k0 = lane * 2;
    float a0 = ps1[g * F + k0], a1 = ps1[g * F + k0 + 1];
    float c0v = ps2[g * F + k0], c1v = ps2[g * F + k0 + 1];
    float p0 = a0 * W4l[k0 * 2 + 0] + a1 * W4l[(k0 + 1) * 2 + 0] +
               c0v * W4r[k0 * 2 + 0] + c1v * W4r[(k0 + 1) * 2 + 0];
    float p1 = a0 * W4l[k0 * 2 + 1] + a1 * W4l[(k0 + 1) * 2 + 1] +
               c0v * W4r[k0 * 2 + 1] + c1v * W4r[(k0 + 1) * 2 + 1];
#pragma unroll
    for (int off = 32; off > 0; off >>= 1) {
        p0 += __shfl_down(p0, off);
        p1 += __shfl_down(p1, off);
    }
    if (lane == 0) {
        out[g * 2 + 0] = p0 + b4[0];
        out[g * 2 + 1] = p1 + b4[1];
    }
}

// ---------------- launcher ----------------

extern "C" void kernel_launch(void* const* d_in, const int* in_sizes, int n_in,
                              void* d_out, int out_size, void* d_ws, size_t ws_size,
                              hipStream_t stream)
{
    (void)n_in; (void)out_size; (void)ws_size;
    const float* x    = (const float*)d_in[0];
    const int*   ei   = (const int*)d_in[1];
    const int*   batch= (const int*)d_in[2];
    const float* W1l = (const float*)d_in[3];
    const float* W1r = (const float*)d_in[4];
    const float* b1  = (const float*)d_in[5];
    const float* W2l = (const float*)d_in[6];
    const float* W2r = (const float*)d_in[7];
    const float* b2  = (const float*)d_in[8];
    const float* W3l = (const float*)d_in[9];
    const float* W3r = (const float*)d_in[10];
    const float* b3  = (const float*)d_in[11];
    const float* W4l = (const float*)d_in[12];
    const float* W4r = (const float*)d_in[13];
    const float* b4  = (const float*)d_in[14];
    float* out = (float*)d_out;

    const int N = in_sizes[0] / F;   // 50000
    const int E = in_sizes[1] / 2;   // 600000
    const int NG = NGRAPH;
    const int* src = ei;
    const int* dst = ei + E;

    char* p = (char*)d_ws;
    auto alloc = [&](size_t bytes) {
        char* r = p;
        p += (bytes + 255) & ~(size_t)255;
        return r;
    };
    int* counts  = (int*)alloc((size_t)N * 4);
    int* rs      = (int*)alloc((size_t)(N + 1) * 4);
    int* cursor  = (int*)alloc((size_t)N * 4);
    int* csr     = (int*)alloc((size_t)E * 4);
    int* gstart  = (int*)alloc((size_t)(NG + 1) * 4);
    float* A     = (float*)alloc((size_t)N * F * 4);  // hl
    float* B     = (float*)alloc((size_t)N * F * 4);  // hr
    float* C     = (float*)alloc((size_t)N * F * 4);  // h (current features)
    float* ps1   = (float*)alloc((size_t)NG * F * 4);
    float* ps2   = (float*)alloc((size_t)NG * F * 4);

    // CSR + graph bounds (rebuilt every call; no static state)
    k_zero<<<dim3((N + 255) / 256), dim3(256), 0, stream>>>(counts, gstart, N, NG + 1);
    k_hist<<<dim3(1024), dim3(256), 0, stream>>>(dst, counts, E);
    k_scan<<<dim3(1), dim3(1024), 0, stream>>>(counts, rs, cursor, N);
    k_scatter<<<dim3(1024), dim3(256), 0, stream>>>(src, dst, cursor, csr, E);
    k_bounds<<<dim3((N + 255) / 256), dim3(256), 0, stream>>>(batch, gstart, N);
    k_fixb<<<dim3(1), dim3(1), 0, stream>>>(gstart, NG, N);

    const int gemmgrid = (N + 63) / 64;
    const int agggrid  = (N + 1) / 2;

    // Layer 1
    k_gemm_dual<<<dim3(gemmgrid), dim3(256), 0, stream>>>(x, W1l, W1r, b1, A, B, N);
    k_agg<1, 1><<<dim3(agggrid), dim3(256), 0, stream>>>(A, B, rs, csr, C, N);
    // Layer 2
    k_gemm_dual<<<dim3(gemmgrid), dim3(256), 0, stream>>>(C, W2l, W2r, b2, A, B, N);
    k_agg<1, 1><<<dim3(agggrid), dim3(256), 0, stream>>>(A, B, rs, csr, C, N);
    // Layer 3
    k_gemm_dual<<<dim3(gemmgrid), dim3(256), 0, stream>>>(C, W3l, W3r, b3, A, B, N);
    k_agg<1, 1><<<dim3(agggrid), dim3(256), 0, stream>>>(A, B, rs, csr, C, N);
    // Layer 4: pooled formulation — agg4 = seg-mean of h3; pool both; tiny GEMM.
    k_agg<0, 0><<<dim3(agggrid), dim3(256), 0, stream>>>(C, nullptr, rs, csr, A, N);
    k_pool<<<dim3(NG), dim3(F), 0, stream>>>(A, C, gstart, ps1, ps2);
    k_final<<<dim3(NG / 4), dim3(256), 0, stream>>>(ps1, ps2, W4l, W4r, b4, out, NG);
}

// Round 3
// 635.043 us; speedup vs baseline: 1.7244x; 1.7244x over previous
//
#include <hip/hip_runtime.h>

#define F 128
#define NGRAPH 512

// ---------------- CSR build ----------------

__global__ void k_zero(int* __restrict__ counts, int n) {
    int i = blockIdx.x * blockDim.x + threadIdx.x;
    if (i < n) counts[i] = 0;
}

__global__ void k_hist(const int* __restrict__ dst, int* __restrict__ counts, int e) {
    for (int i = blockIdx.x * blockDim.x + threadIdx.x; i < e; i += gridDim.x * blockDim.x)
        atomicAdd(&counts[dst[i]], 1);
}

// Hierarchical scan: block sums -> scan of block sums -> apply.
__global__ __launch_bounds__(256) void k_bsum(const int* __restrict__ counts,
                                              int* __restrict__ bsum, int n) {
    __shared__ int sm[256];
    const int t = threadIdx.x;
    int i = blockIdx.x * 256 + t;
    sm[t] = (i < n) ? counts[i] : 0;
    __syncthreads();
    for (int off = 128; off > 0; off >>= 1) {
        if (t < off) sm[t] += sm[t + off];
        __syncthreads();
    }
    if (t == 0) bsum[blockIdx.x] = sm[0];
}

__global__ __launch_bounds__(256) void k_scanb(const int* __restrict__ bsum,
                                               int* __restrict__ boff, int nb,
                                               int* __restrict__ rs, int n) {
    __shared__ int sm[256];
    const int t = threadIdx.x;
    const int npt = (nb + 255) >> 8;
    const int base = t * npt;
    int s = 0;
    for (int i = 0; i < npt; i++) { int idx = base + i; if (idx < nb) s += bsum[idx]; }
    sm[t] = s;
    __syncthreads();
    for (int off = 1; off < 256; off <<= 1) {
        int u = (t >= off) ? sm[t - off] : 0;
        __syncthreads();
        sm[t] += u;
        __syncthreads();
    }
    int run = (t == 0) ? 0 : sm[t - 1];
    for (int i = 0; i < npt; i++) {
        int idx = base + i;
        if (idx < nb) { boff[idx] = run; run += bsum[idx]; }
    }
    if (t == 255) rs[n] = sm[255];
}

__global__ __launch_bounds__(256) void k_apply(const int* __restrict__ counts,
                                               const int* __restrict__ boff,
                                               int* __restrict__ rs,
                                               int* __restrict__ cursor, int n) {
    __shared__ int sm[256];
    const int t = threadIdx.x;
    int i = blockIdx.x * 256 + t;
    int v = (i < n) ? counts[i] : 0;
    sm[t] = v;
    __syncthreads();
    for (int off = 1; off < 256; off <<= 1) {
        int u = (t >= off) ? sm[t - off] : 0;
        __syncthreads();
        sm[t] += u;
        __syncthreads();
    }
    int excl = sm[t] - v + boff[blockIdx.x];
    if (i < n) { rs[i] = excl; cursor[i] = excl; }
}

__global__ void k_scatter(const int* __restrict__ src, const int* __restrict__ dst,
                          int* __restrict__ cursor, int* __restrict__ csr, int e) {
    for (int i = blockIdx.x * blockDim.x + threadIdx.x; i < e; i += gridDim.x * blockDim.x) {
        int p = atomicAdd(&cursor[dst[i]], 1);
        csr[p] = src[i];
    }
}

// gstart[g] = lower_bound(batch, g) via binary search (batch is sorted).
__global__ void k_gbounds(const int* __restrict__ batch, int* __restrict__ gstart,
                          int n, int ng) {
    int g = blockIdx.x * blockDim.x + threadIdx.x;
    if (g > ng) return;
    if (g == ng) { gstart[ng] = n; return; }
    int lo = 0, hi = n;
    while (lo < hi) {
        int mid = (lo + hi) >> 1;
        if (batch[mid] < g) lo = mid + 1; else hi = mid;
    }
    gstart[g] = lo;
}

// ---------------- dual GEMM: hl = h@Wl, hr = h@Wr + b ----------------

__global__ __launch_bounds__(256) void k_gemm_dual(
    const float* __restrict__ h, const float* __restrict__ Wl,
    const float* __restrict__ Wr, const float* __restrict__ bias,
    float* __restrict__ hl, float* __restrict__ hr, int nrows)
{
    __shared__ float xs[64][F];
    const int t = threadIdx.x;
    const int row0 = blockIdx.x * 64;
    {
        const int nv = 64 * F / 4;  // 2048 float4
        const float4* srcp = (const float4*)(h + (size_t)row0 * F);
        float4* dl = (float4*)&xs[0][0];
        for (int i = t; i < nv; i += 256) {
            int r = i >> 5;  // 32 float4 per row
            float4 v;
            if (row0 + r < nrows) v = srcp[i];
            else v = make_float4(0.f, 0.f, 0.f, 0.f);
            dl[i] = v;
        }
    }
    __syncthreads();
    const int cg = t & 31, rg = t >> 5;
    const int c0 = cg * 4, r0 = rg * 8;
    float accl[8][4] = {};
    float accr[8][4] = {};
#pragma unroll 2
    for (int k = 0; k < F; k++) {
        const float4 wl = *(const float4*)&Wl[k * F + c0];
        const float4 wr = *(const float4*)&Wr[k * F + c0];
#pragma unroll
        for (int r = 0; r < 8; r++) {
            const float xv = xs[r0 + r][k];
            accl[r][0] = fmaf(xv, wl.x, accl[r][0]);
            accl[r][1] = fmaf(xv, wl.y, accl[r][1]);
            accl[r][2] = fmaf(xv, wl.z, accl[r][2]);
            accl[r][3] = fmaf(xv, wl.w, accl[r][3]);
            accr[r][0] = fmaf(xv, wr.x, accr[r][0]);
            accr[r][1] = fmaf(xv, wr.y, accr[r][1]);
            accr[r][2] = fmaf(xv, wr.z, accr[r][2]);
            accr[r][3] = fmaf(xv, wr.w, accr[r][3]);
        }
    }
    const float4 bv = *(const float4*)&bias[c0];
#pragma unroll
    for (int r = 0; r < 8; r++) {
        int row = row0 + r0 + r;
        if (row < nrows) {
            float4 vl = make_float4(accl[r][0], accl[r][1], accl[r][2], accl[r][3]);
            float4 vr = make_float4(accr[r][0] + bv.x, accr[r][1] + bv.y,
                                    accr[r][2] + bv.z, accr[r][3] + bv.w);
            *(float4*)&hl[(size_t)row * F + c0] = vl;
            *(float4*)&hr[(size_t)row * F + c0] = vr;
        }
    }
}

// ---------------- aggregation ----------------
// out[v] = (relu?)(sum_e hl[csr[e]]/deg (+ hr[v]))
// float4 lanes: 32 threads per node, 8 nodes per 256-thread block.
// 4-way unrolled edge loop -> 4 outstanding row gathers (MLP).

__device__ __forceinline__ void acc4(float4& s, const float4 v) {
    s.x += v.x; s.y += v.y; s.z += v.z; s.w += v.w;
}

template <int RELU, int HASR>
__global__ __launch_bounds__(256) void k_agg(
    const float* __restrict__ hlf, const float* __restrict__ hrf,
    const int* __restrict__ rs, const int* __restrict__ csr,
    float* __restrict__ outf, int nnodes)
{
    const int FV = F / 4;  // 32 float4 per row
    const float4* hl = (const float4*)hlf;
    const float4* hr = (const float4*)hrf;
    float4* out = (float4*)outf;

    int v = blockIdx.x * 8 + (threadIdx.x >> 5);
    if (v >= nnodes) return;
    int c = threadIdx.x & 31;
    int e0 = rs[v], e1 = rs[v + 1];

    float4 s0 = make_float4(0.f, 0.f, 0.f, 0.f);
    float4 s1 = s0, s2 = s0, s3 = s0;
    int e = e0;
    for (; e + 4 <= e1; e += 4) {
        int a = csr[e], b = csr[e + 1], cc = csr[e + 2], d = csr[e + 3];
        acc4(s0, hl[(size_t)a * FV + c]);
        acc4(s1, hl[(size_t)b * FV + c]);
        acc4(s2, hl[(size_t)cc * FV + c]);
        acc4(s3, hl[(size_t)d * FV + c]);
    }
    for (; e < e1; e++) acc4(s0, hl[(size_t)csr[e] * FV + c]);
    acc4(s0, s1); acc4(s2, s3); acc4(s0, s2);

    const float inv = 1.f / (float)max(e1 - e0, 1);
    float4 o = make_float4(s0.x * inv, s0.y * inv, s0.z * inv, s0.w * inv);
    if (HASR) {
        float4 r = hr[(size_t)v * FV + c];
        o.x += r.x; o.y += r.y; o.z += r.z; o.w += r.w;
    }
    if (RELU) {
        o.x = fmaxf(o.x, 0.f); o.y = fmaxf(o.y, 0.f);
        o.z = fmaxf(o.z, 0.f); o.w = fmaxf(o.w, 0.f);
    }
    out[(size_t)v * FV + c] = o;
}

// ---------------- per-graph mean pool of tagg (=agg4) and h3 ----------------

__global__ void k_pool(const float* __restrict__ tagg, const float* __restrict__ h3,
                       const int* __restrict__ gstart,
                       float* __restrict__ ps1, float* __restrict__ ps2)
{
    int g = blockIdx.x, c = threadIdx.x;  // 128 threads
    int v0 = gstart[g], v1 = gstart[g + 1];
    float s1 = 0.f, s2 = 0.f;
    for (int v = v0; v < v1; v++) {
        s1 += tagg[(size_t)v * F + c];
        s2 += h3[(size_t)v * F + c];
    }
    float inv = 1.f / (float)max(v1 - v0, 1);
    ps1[g * F + c] = s1 * inv;
    ps2[g * F + c] = s2 * inv;
}

// ---------------- final tiny GEMM: out = ps1@W4l + ps2@W4r + b4 ----------------

__global__ void k_final(const float* __restrict__ ps1, const float* __restrict__ ps2,
                        const float* __restrict__ W4l, const float* __restrict__ W4r,
                        const float* __restrict__ b4, float* __restrict__ out, int ngraph)
{
    int g = blockIdx.x * 4 + (threadIdx.x >> 6);
    int lane = threadIdx.x & 63;
    if (g >= ngraph) return;
    int k0 = lane * 2;
    float a0 = ps1[g * F + k0], a1 = ps1[g * F + k0 + 1];
    float c0v = ps2[g * F + k0], c1v = ps2[g * F + k0 + 1];
    float p0 = a0 * W4l[k0 * 2 + 0] + a1 * W4l[(k0 + 1) * 2 + 0] +
               c0v * W4r[k0 * 2 + 0] + c1v * W4r[(k0 + 1) * 2 + 0];
    float p1 = a0 * W4l[k0 * 2 + 1] + a1 * W4l[(k0 + 1) * 2 + 1] +
               c0v * W4r[k0 * 2 + 1] + c1v * W4r[(k0 + 1) * 2 + 1];
#pragma unroll
    for (int off = 32; off > 0; off >>= 1) {
        p0 += __shfl_down(p0, off);
        p1 += __shfl_down(p1, off);
    }
    if (lane == 0) {
        out[g * 2 + 0] = p0 + b4[0];
        out[g * 2 + 1] = p1 + b4[1];
    }
}

// ---------------- launcher ----------------

extern "C" void kernel_launch(void* const* d_in, const int* in_sizes, int n_in,
                              void* d_out, int out_size, void* d_ws, size_t ws_size,
                              hipStream_t stream)
{
    (void)n_in; (void)out_size; (void)ws_size;
    const float* x    = (const float*)d_in[0];
    const int*   ei   = (const int*)d_in[1];
    const int*   batch= (const int*)d_in[2];
    const float* W1l = (const float*)d_in[3];
    const float* W1r = (const float*)d_in[4];
    const float* b1  = (const float*)d_in[5];
    const float* W2l = (const float*)d_in[6];
    const float* W2r = (const float*)d_in[7];
    const float* b2  = (const float*)d_in[8];
    const float* W3l = (const float*)d_in[9];
    const float* W3r = (const float*)d_in[10];
    const float* b3  = (const float*)d_in[11];
    const float* W4l = (const float*)d_in[12];
    const float* W4r = (const float*)d_in[13];
    const float* b4  = (const float*)d_in[14];
    float* out = (float*)d_out;

    const int N = in_sizes[0] / F;   // 50000
    const int E = in_sizes[1] / 2;   // 600000
    const int NG = NGRAPH;
    const int* src = ei;
    const int* dst = ei + E;
    const int NB = (N + 255) / 256;  // scan blocks

    char* p = (char*)d_ws;
    auto alloc = [&](size_t bytes) {
        char* r = p;
        p += (bytes + 255) & ~(size_t)255;
        return r;
    };
    int* counts  = (int*)alloc((size_t)N * 4);
    int* rs      = (int*)alloc((size_t)(N + 1) * 4);
    int* cursor  = (int*)alloc((size_t)N * 4);
    int* csr     = (int*)alloc((size_t)E * 4);
    int* gstart  = (int*)alloc((size_t)(NG + 1) * 4);
    int* bsum    = (int*)alloc((size_t)NB * 4);
    int* boff    = (int*)alloc((size_t)NB * 4);
    float* A     = (float*)alloc((size_t)N * F * 4);  // hl
    float* B     = (float*)alloc((size_t)N * F * 4);  // hr
    float* C     = (float*)alloc((size_t)N * F * 4);  // h (current features)
    float* ps1   = (float*)alloc((size_t)NG * F * 4);
    float* ps2   = (float*)alloc((size_t)NG * F * 4);

    // CSR + graph bounds (rebuilt every call; no static state)
    k_zero<<<dim3((N + 255) / 256), dim3(256), 0, stream>>>(counts, N);
    k_hist<<<dim3(1024), dim3(256), 0, stream>>>(dst, counts, E);
    k_bsum<<<dim3(NB), dim3(256), 0, stream>>>(counts, bsum, N);
    k_scanb<<<dim3(1), dim3(256), 0, stream>>>(bsum, boff, NB, rs, N);
    k_apply<<<dim3(NB), dim3(256), 0, stream>>>(counts, boff, rs, cursor, N);
    k_scatter<<<dim3(1024), dim3(256), 0, stream>>>(src, dst, cursor, csr, E);
    k_gbounds<<<dim3((NG + 256) / 256), dim3(256), 0, stream>>>(batch, gstart, N, NG);

    const int gemmgrid = (N + 63) / 64;
    const int agggrid  = (N + 7) / 8;

    // Layer 1
    k_gemm_dual<<<dim3(gemmgrid), dim3(256), 0, stream>>>(x, W1l, W1r, b1, A, B, N);
    k_agg<1, 1><<<dim3(agggrid), dim3(256), 0, stream>>>(A, B, rs, csr, C, N);
    // Layer 2
    k_gemm_dual<<<dim3(gemmgrid), dim3(256), 0, stream>>>(C, W2l, W2r, b2, A, B, N);
    k_agg<1, 1><<<dim3(agggrid), dim3(256), 0, stream>>>(A, B, rs, csr, C, N);
    // Layer 3
    k_gemm_dual<<<dim3(gemmgrid), dim3(256), 0, stream>>>(C, W3l, W3r, b3, A, B, N);
    k_agg<1, 1><<<dim3(agggrid), dim3(256), 0, stream>>>(A, B, rs, csr, C, N);
    // Layer 4: pooled formulation — agg4 = seg-mean of h3; pool both; tiny GEMM.
    k_agg<0, 0><<<dim3(agggrid), dim3(256), 0, stream>>>(C, nullptr, rs, csr, A, N);
    k_pool<<<dim3(NG), dim3(F), 0, stream>>>(A, C, gstart, ps1, ps2);
    k_final<<<dim3(NG / 4), dim3(256), 0, stream>>>(ps1, ps2, W4l, W4r, b4, out, NG);
}

// Round 5
// 491.354 us; speedup vs baseline: 2.2286x; 1.2924x over previous
//
#include <hip/hip_runtime.h>

#define F 128
#define NGRAPH 512

typedef __attribute__((ext_vector_type(8))) __bf16 bf16x8;
typedef __attribute__((ext_vector_type(4))) float f32x4;

// ---- bf16 helpers (RTNE, no NaN handling needed for this data) ----
__device__ __forceinline__ unsigned short f2bf(float f) {
    unsigned int u = __float_as_uint(f);
    u = (u + 0x7fffu + ((u >> 16) & 1u)) >> 16;
    return (unsigned short)u;
}
__device__ __forceinline__ float bf2f(unsigned short b) {
    return __uint_as_float(((unsigned int)b) << 16);
}

// ---------------- CSR build ----------------

__global__ void k_zero(int* __restrict__ counts, int n) {
    int i = blockIdx.x * blockDim.x + threadIdx.x;
    if (i < n) counts[i] = 0;
}

__global__ void k_hist(const int* __restrict__ dst, int* __restrict__ counts, int e) {
    for (int i = blockIdx.x * blockDim.x + threadIdx.x; i < e; i += gridDim.x * blockDim.x)
        atomicAdd(&counts[dst[i]], 1);
}

__global__ __launch_bounds__(256) void k_bsum(const int* __restrict__ counts,
                                              int* __restrict__ bsum, int n) {
    __shared__ int sm[256];
    const int t = threadIdx.x;
    int i = blockIdx.x * 256 + t;
    sm[t] = (i < n) ? counts[i] : 0;
    __syncthreads();
    for (int off = 128; off > 0; off >>= 1) {
        if (t < off) sm[t] += sm[t + off];
        __syncthreads();
    }
    if (t == 0) bsum[blockIdx.x] = sm[0];
}

__global__ __launch_bounds__(256) void k_scanb(const int* __restrict__ bsum,
                                               int* __restrict__ boff, int nb,
                                               int* __restrict__ rs, int n) {
    __shared__ int sm[256];
    const int t = threadIdx.x;
    const int npt = (nb + 255) >> 8;
    const int base = t * npt;
    int s = 0;
    for (int i = 0; i < npt; i++) { int idx = base + i; if (idx < nb) s += bsum[idx]; }
    sm[t] = s;
    __syncthreads();
    for (int off = 1; off < 256; off <<= 1) {
        int u = (t >= off) ? sm[t - off] : 0;
        __syncthreads();
        sm[t] += u;
        __syncthreads();
    }
    int run = (t == 0) ? 0 : sm[t - 1];
    for (int i = 0; i < npt; i++) {
        int idx = base + i;
        if (idx < nb) { boff[idx] = run; run += bsum[idx]; }
    }
    if (t == 255) rs[n] = sm[255];
}

__global__ __launch_bounds__(256) void k_apply(const int* __restrict__ counts,
                                               const int* __restrict__ boff,
                                               int* __restrict__ rs,
                                               int* __restrict__ cursor, int n) {
    __shared__ int sm[256];
    const int t = threadIdx.x;
    int i = blockIdx.x * 256 + t;
    int v = (i < n) ? counts[i] : 0;
    sm[t] = v;
    __syncthreads();
    for (int off = 1; off < 256; off <<= 1) {
        int u = (t >= off) ? sm[t - off] : 0;
        __syncthreads();
        sm[t] += u;
        __syncthreads();
    }
    int excl = sm[t] - v + boff[blockIdx.x];
    if (i < n) { rs[i] = excl; cursor[i] = excl; }
}

__global__ void k_scatter(const int* __restrict__ src, const int* __restrict__ dst,
                          int* __restrict__ cursor, int* __restrict__ csr, int e) {
    for (int i = blockIdx.x * blockDim.x + threadIdx.x; i < e; i += gridDim.x * blockDim.x) {
        int p = atomicAdd(&cursor[dst[i]], 1);
        csr[p] = src[i];
    }
}

__global__ void k_gbounds(const int* __restrict__ batch, int* __restrict__ gstart,
                          int n, int ng) {
    int g = blockIdx.x * blockDim.x + threadIdx.x;
    if (g > ng) return;
    if (g == ng) { gstart[ng] = n; return; }
    int lo = 0, hi = n;
    while (lo < hi) {
        int mid = (lo + hi) >> 1;
        if (batch[mid] < g) lo = mid + 1; else hi = mid;
    }
    gstart[g] = lo;
}

// ---------------- weight prep: split fp32 W into bf16 hi/lo, fragment-major ----------------
// frag-major: for n-tile nt(0..7), k-step ks(0..7), lane l(0..63), j(0..7):
//   element index = ((nt*8+ks)*64 + l)*8 + j  holds  Wcat[ks*32+(l>>4)*8+j][nt*16+(l&15)]
// where Wcat rows 0..127 = Wl, 128..255 = Wr.

__global__ __launch_bounds__(256) void k_wprep(const float* __restrict__ Wl,
                                               const float* __restrict__ Wr,
                                               unsigned short* __restrict__ whi,
                                               unsigned short* __restrict__ wlo) {
    int tid = blockIdx.x * 256 + threadIdx.x;   // 0 .. 32767
    if (tid >= 8 * 8 * 64 * 8) return;
    int j = tid & 7;
    int fp = tid >> 3;
    int l = fp & 63;
    int ks = (fp >> 6) & 7;
    int nt = fp >> 9;
    int k = ks * 32 + ((l >> 4) << 3) + j;
    int n = nt * 16 + (l & 15);
    float v = (k < F) ? Wl[k * F + n] : Wr[(k - F) * F + n];
    unsigned short hi = f2bf(v);
    unsigned short lo = f2bf(v - bf2f(hi));
    whi[tid] = hi;
    wlo[tid] = lo;
}

// ---------------- fused MFMA GEMM: C = relu(Aagg@Wl + Bh@Wr + bias) ----------------
// K = 256 (concat [Aagg | Bh]); split-bf16 3-pass: hi@hi + hi@lo + lo@hi.
// Block: 256 threads (4 waves), 64 output rows x 128 cols.
// Wave w owns col-tiles nt in {2w, 2w+1}, all 64 rows (4 row-tiles).
// LDS: A-tile hi+lo bf16, XOR-swizzled (idx ^= (row&7)<<3 at 8-elem grain).

__global__ __launch_bounds__(256, 2) void k_gemm_fused(
    const float* __restrict__ Aagg, const float* __restrict__ Bh,
    const unsigned short* __restrict__ whi, const unsigned short* __restrict__ wlo,
    const float* __restrict__ bias, float* __restrict__ Cout, int nrows)
{
    __shared__ unsigned short ahi[64 * 256];
    __shared__ unsigned short alo[64 * 256];
    const int t = threadIdx.x;
    const int row0 = blockIdx.x * 64;

    // ---- stage 64 rows x 256 k (A then Bh), fp32 -> bf16 hi/lo, swizzled ----
    {
        const float4* Av = (const float4*)Aagg;
        const float4* Bv = (const float4*)Bh;
        const float4 z = make_float4(0.f, 0.f, 0.f, 0.f);
#pragma unroll
        for (int it = 0; it < 8; it++) {
            int i = t + 256 * it;          // 0..2047
            int row = i >> 5;              // 0..63
            int c4 = i & 31;               // float4 index within 128
            bool ok = (row0 + row) < nrows;
            float4 va = ok ? Av[(size_t)(row0 + row) * 32 + c4] : z;
            float4 vb = ok ? Bv[(size_t)(row0 + row) * 32 + c4] : z;
            int swz = (row & 7) << 3;
            ushort4 h4, l4;
            h4.x = f2bf(va.x); l4.x = f2bf(va.x - bf2f(h4.x));
            h4.y = f2bf(va.y); l4.y = f2bf(va.y - bf2f(h4.y));
            h4.z = f2bf(va.z); l4.z = f2bf(va.z - bf2f(h4.z));
            h4.w = f2bf(va.w); l4.w = f2bf(va.w - bf2f(h4.w));
            int ia = row * 256 + ((c4 * 4) ^ swz);
            *(ushort4*)&ahi[ia] = h4;
            *(ushort4*)&alo[ia] = l4;
            h4.x = f2bf(vb.x); l4.x = f2bf(vb.x - bf2f(h4.x));
            h4.y = f2bf(vb.y); l4.y = f2bf(vb.y - bf2f(h4.y));
            h4.z = f2bf(vb.z); l4.z = f2bf(vb.z - bf2f(h4.z));
            h4.w = f2bf(vb.w); l4.w = f2bf(vb.w - bf2f(h4.w));
            int ib = row * 256 + ((128 + c4 * 4) ^ swz);
            *(ushort4*)&ahi[ib] = h4;
            *(ushort4*)&alo[ib] = l4;
        }
    }
    __syncthreads();

    const int w = t >> 6;
    const int l = t & 63;
    const int lm = l & 15;
    const int lk = l >> 4;
    const bf16x8* whiv = (const bf16x8*)whi;
    const bf16x8* wlov = (const bf16x8*)wlo;

    f32x4 acc[4][2];
#pragma unroll
    for (int rt = 0; rt < 4; rt++)
#pragma unroll
        for (int j = 0; j < 2; j++) acc[rt][j] = (f32x4)(0.f);

    for (int ks = 0; ks < 8; ks++) {
        const int kidx = ks * 32 + lk * 8;
        bf16x8 ah[4], al[4];
#pragma unroll
        for (int rt = 0; rt < 4; rt++) {
            int row = rt * 16 + lm;
            int idx = row * 256 + (kidx ^ ((row & 7) << 3));
            ah[rt] = *(const bf16x8*)&ahi[idx];
            al[rt] = *(const bf16x8*)&alo[idx];
        }
#pragma unroll
        for (int j = 0; j < 2; j++) {
            int nt = 2 * w + j;
            bf16x8 wh = whiv[(nt * 8 + ks) * 64 + l];
            bf16x8 wl = wlov[(nt * 8 + ks) * 64 + l];
#pragma unroll
            for (int rt = 0; rt < 4; rt++) {
                acc[rt][j] = __builtin_amdgcn_mfma_f32_16x16x32_bf16(ah[rt], wh, acc[rt][j], 0, 0, 0);
                acc[rt][j] = __builtin_amdgcn_mfma_f32_16x16x32_bf16(ah[rt], wl, acc[rt][j], 0, 0, 0);
                acc[rt][j] = __builtin_amdgcn_mfma_f32_16x16x32_bf16(al[rt], wh, acc[rt][j], 0, 0, 0);
            }
        }
    }

    // ---- epilogue: + bias, relu, store ----
#pragma unroll
    for (int j = 0; j < 2; j++) {
        int col = (2 * w + j) * 16 + lm;
        float bv = bias[col];
#pragma unroll
        for (int rt = 0; rt < 4; rt++) {
#pragma unroll
            for (int r = 0; r < 4; r++) {
                int row = row0 + rt * 16 + lk * 4 + r;
                if (row < nrows) {
                    float v = acc[rt][j][r] + bv;
                    v = fmaxf(v, 0.f);
                    Cout[(size_t)row * F + col] = v;
                }
            }
        }
    }
}

// ---------------- aggregation: out[v] = mean over neighbors of hl ----------------

__device__ __forceinline__ void acc4(float4& s, const float4 v) {
    s.x += v.x; s.y += v.y; s.z += v.z; s.w += v.w;
}

__global__ __launch_bounds__(256) void k_aggm(
    const float* __restrict__ hlf, const int* __restrict__ rs,
    const int* __restrict__ csr, float* __restrict__ outf, int nnodes)
{
    const int FV = F / 4;
    const float4* hl = (const float4*)hlf;
    float4* out = (float4*)outf;

    int v = blockIdx.x * 8 + (threadIdx.x >> 5);
    if (v >= nnodes) return;
    int c = threadIdx.x & 31;
    int e0 = rs[v], e1 = rs[v + 1];

    float4 s0 = make_float4(0.f, 0.f, 0.f, 0.f);
    float4 s1 = s0, s2 = s0, s3 = s0;
    int e = e0;
    for (; e + 4 <= e1; e += 4) {
        int a = csr[e], b = csr[e + 1], cc = csr[e + 2], d = csr[e + 3];
        acc4(s0, hl[(size_t)a * FV + c]);
        acc4(s1, hl[(size_t)b * FV + c]);
        acc4(s2, hl[(size_t)cc * FV + c]);
        acc4(s3, hl[(size_t)d * FV + c]);
    }
    for (; e < e1; e++) acc4(s0, hl[(size_t)csr[e] * FV + c]);
    acc4(s0, s1); acc4(s2, s3); acc4(s0, s2);

    const float inv = 1.f / (float)max(e1 - e0, 1);
    out[(size_t)v * FV + c] = make_float4(s0.x * inv, s0.y * inv, s0.z * inv, s0.w * inv);
}

// ---------------- per-graph mean pool ----------------

__global__ void k_pool(const float* __restrict__ tagg, const float* __restrict__ h3,
                       const int* __restrict__ gstart,
                       float* __restrict__ ps1, float* __restrict__ ps2)
{
    int g = blockIdx.x, c = threadIdx.x;  // 128 threads
    int v0 = gstart[g], v1 = gstart[g + 1];
    float s1 = 0.f, s2 = 0.f;
    for (int v = v0; v < v1; v++) {
        s1 += tagg[(size_t)v * F + c];
        s2 += h3[(size_t)v * F + c];
    }
    float inv = 1.f / (float)max(v1 - v0, 1);
    ps1[g * F + c] = s1 * inv;
    ps2[g * F + c] = s2 * inv;
}

// ---------------- final tiny GEMM ----------------

__global__ void k_final(const float* __restrict__ ps1, const float* __restrict__ ps2,
                        const float* __restrict__ W4l, const float* __restrict__ W4r,
                        const float* __restrict__ b4, float* __restrict__ out, int ngraph)
{
    int g = blockIdx.x * 4 + (threadIdx.x >> 6);
    int lane = threadIdx.x & 63;
    if (g >= ngraph) return;
    int k0 = lane * 2;
    float a0 = ps1[g * F + k0], a1 = ps1[g * F + k0 + 1];
    float c0v = ps2[g * F + k0], c1v = ps2[g * F + k0 + 1];
    float p0 = a0 * W4l[k0 * 2 + 0] + a1 * W4l[(k0 + 1) * 2 + 0] +
               c0v * W4r[k0 * 2 + 0] + c1v * W4r[(k0 + 1) * 2 + 0];
    float p1 = a0 * W4l[k0 * 2 + 1] + a1 * W4l[(k0 + 1) * 2 + 1] +
               c0v * W4r[k0 * 2 + 1] + c1v * W4r[(k0 + 1) * 2 + 1];
#pragma unroll
    for (int off = 32; off > 0; off >>= 1) {
        p0 += __shfl_down(p0, off);
        p1 += __shfl_down(p1, off);
    }
    if (lane == 0) {
        out[g * 2 + 0] = p0 + b4[0];
        out[g * 2 + 1] = p1 + b4[1];
    }
}

// ---------------- launcher ----------------

extern "C" void kernel_launch(void* const* d_in, const int* in_sizes, int n_in,
                              void* d_out, int out_size, void* d_ws, size_t ws_size,
                              hipStream_t stream)
{
    (void)n_in; (void)out_size; (void)ws_size;
    const float* x    = (const float*)d_in[0];
    const int*   ei   = (const int*)d_in[1];
    const int*   batch= (const int*)d_in[2];
    const float* W1l = (const float*)d_in[3];
    const float* W1r = (const float*)d_in[4];
    const float* b1  = (const float*)d_in[5];
    const float* W2l = (const float*)d_in[6];
    const float* W2r = (const float*)d_in[7];
    const float* b2  = (const float*)d_in[8];
    const float* W3l = (const float*)d_in[9];
    const float* W3r = (const float*)d_in[10];
    const float* b3  = (const float*)d_in[11];
    const float* W4l = (const float*)d_in[12];
    const float* W4r = (const float*)d_in[13];
    const float* b4  = (const float*)d_in[14];
    float* out = (float*)d_out;

    const int N = in_sizes[0] / F;   // 50000
    const int E = in_sizes[1] / 2;   // 600000
    const int NG = NGRAPH;
    const int* src = ei;
    const int* dst = ei + E;
    const int NB = (N + 255) / 256;

    char* p = (char*)d_ws;
    auto alloc = [&](size_t bytes) {
        char* r = p;
        p += (bytes + 255) & ~(size_t)255;
        return r;
    };
    int* counts  = (int*)alloc((size_t)N * 4);
    int* rs      = (int*)alloc((size_t)(N + 1) * 4);
    int* cursor  = (int*)alloc((size_t)N * 4);
    int* csr     = (int*)alloc((size_t)E * 4);
    int* gstart  = (int*)alloc((size_t)(NG + 1) * 4);
    int* bsum    = (int*)alloc((size_t)NB * 4);
    int* boff    = (int*)alloc((size_t)NB * 4);
    const size_t WSPLIT = 8 * 8 * 64 * 8;  // 32768 ushorts = 64KB
    unsigned short* w1hi = (unsigned short*)alloc(WSPLIT * 2);
    unsigned short* w1lo = (unsigned short*)alloc(WSPLIT * 2);
    unsigned short* w2hi = (unsigned short*)alloc(WSPLIT * 2);
    unsigned short* w2lo = (unsigned short*)alloc(WSPLIT * 2);
    unsigned short* w3hi = (unsigned short*)alloc(WSPLIT * 2);
    unsigned short* w3lo = (unsigned short*)alloc(WSPLIT * 2);
    float* Agg   = (float*)alloc((size_t)N * F * 4);
    float* B     = (float*)alloc((size_t)N * F * 4);
    float* C     = (float*)alloc((size_t)N * F * 4);
    float* ps1   = (float*)alloc((size_t)NG * F * 4);
    float* ps2   = (float*)alloc((size_t)NG * F * 4);

    // Weight split (independent of CSR chain)
    k_wprep<<<dim3(128), dim3(256), 0, stream>>>(W1l, W1r, w1hi, w1lo);
    k_wprep<<<dim3(128), dim3(256), 0, stream>>>(W2l, W2r, w2hi, w2lo);
    k_wprep<<<dim3(128), dim3(256), 0, stream>>>(W3l, W3r, w3hi, w3lo);

    // CSR + graph bounds
    k_zero<<<dim3((N + 255) / 256), dim3(256), 0, stream>>>(counts, N);
    k_hist<<<dim3(1024), dim3(256), 0, stream>>>(dst, counts, E);
    k_bsum<<<dim3(NB), dim3(256), 0, stream>>>(counts, bsum, N);
    k_scanb<<<dim3(1), dim3(256), 0, stream>>>(bsum, boff, NB, rs, N);
    k_apply<<<dim3(NB), dim3(256), 0, stream>>>(counts, boff, rs, cursor, N);
    k_scatter<<<dim3(1024), dim3(256), 0, stream>>>(src, dst, cursor, csr, E);
    k_gbounds<<<dim3((NG + 256) / 256), dim3(256), 0, stream>>>(batch, gstart, N, NG);

    const int gemmgrid = (N + 63) / 64;
    const int agggrid  = (N + 7) / 8;

    // Layer 1: agg(x) -> Agg; C = relu(Agg@W1l + x@W1r + b1)
    k_aggm<<<dim3(agggrid), dim3(256), 0, stream>>>(x, rs, csr, Agg, N);
    k_gemm_fused<<<dim3(gemmgrid), dim3(256), 0, stream>>>(Agg, x, w1hi, w1lo, b1, C, N);
    // Layer 2: B = relu(Agg@W2l + C@W2r + b2)
    k_aggm<<<dim3(agggrid), dim3(256), 0, stream>>>(C, rs, csr, Agg, N);
    k_gemm_fused<<<dim3(gemmgrid), dim3(256), 0, stream>>>(Agg, C, w2hi, w2lo, b2, B, N);
    // Layer 3: C = relu(Agg@W3l + B@W3r + b3)   (C = h3)
    k_aggm<<<dim3(agggrid), dim3(256), 0, stream>>>(B, rs, csr, Agg, N);
    k_gemm_fused<<<dim3(gemmgrid), dim3(256), 0, stream>>>(Agg, B, w3hi, w3lo, b3, C, N);
    // Layer 4 (pooled): Agg = seg-mean(h3); pool; tiny GEMM
    k_aggm<<<dim3(agggrid), dim3(256), 0, stream>>>(C, rs, csr, Agg, N);
    k_pool<<<dim3(NG), dim3(F), 0, stream>>>(Agg, C, gstart, ps1, ps2);
    k_final<<<dim3(NG / 4), dim3(256), 0, stream>>>(ps1, ps2, W4l, W4r, b4, out, NG);
}

// Round 6
// 414.608 us; speedup vs baseline: 2.6411x; 1.1851x over previous
//
#include <hip/hip_runtime.h>

#define F 128
#define NGRAPH 512

typedef __attribute__((ext_vector_type(8))) __bf16 bf16x8;
typedef __attribute__((ext_vector_type(4))) float f32x4;
typedef __attribute__((ext_vector_type(8))) unsigned short u16x8;

// ---- bf16 helpers (RTNE) ----
__device__ __forceinline__ unsigned short f2bf(float f) {
    unsigned int u = __float_as_uint(f);
    u = (u + 0x7fffu + ((u >> 16) & 1u)) >> 16;
    return (unsigned short)u;
}
__device__ __forceinline__ float bf2f(unsigned short b) {
    return __uint_as_float(((unsigned int)b) << 16);
}

// ---------------- CSR build ----------------

__global__ __launch_bounds__(256) void k_hist(const int* __restrict__ dst,
                                              int* __restrict__ counts, int e) {
    int i = blockIdx.x * 256 + threadIdx.x;
    if (i < e) atomicAdd(&counts[dst[i]], 1);
}

__global__ __launch_bounds__(256) void k_bsum(const int* __restrict__ counts,
                                              int* __restrict__ bsum, int n) {
    __shared__ int sm[256];
    const int t = threadIdx.x;
    int i = blockIdx.x * 256 + t;
    sm[t] = (i < n) ? counts[i] : 0;
    __syncthreads();
    for (int off = 128; off > 0; off >>= 1) {
        if (t < off) sm[t] += sm[t + off];
        __syncthreads();
    }
    if (t == 0) bsum[blockIdx.x] = sm[0];
}

__global__ __launch_bounds__(256) void k_scanb(const int* __restrict__ bsum,
                                               int* __restrict__ boff, int nb,
                                               int* __restrict__ rs, int n) {
    __shared__ int sm[256];
    const int t = threadIdx.x;
    const int npt = (nb + 255) >> 8;
    const int base = t * npt;
    int s = 0;
    for (int i = 0; i < npt; i++) { int idx = base + i; if (idx < nb) s += bsum[idx]; }
    sm[t] = s;
    __syncthreads();
    for (int off = 1; off < 256; off <<= 1) {
        int u = (t >= off) ? sm[t - off] : 0;
        __syncthreads();
        sm[t] += u;
        __syncthreads();
    }
    int run = (t == 0) ? 0 : sm[t - 1];
    for (int i = 0; i < npt; i++) {
        int idx = base + i;
        if (idx < nb) { boff[idx] = run; run += bsum[idx]; }
    }
    if (t == 255) rs[n] = sm[255];
}

__global__ __launch_bounds__(256) void k_apply(const int* __restrict__ counts,
                                               const int* __restrict__ boff,
                                               int* __restrict__ rs,
                                               int* __restrict__ cursor, int n) {
    __shared__ int sm[256];
    const int t = threadIdx.x;
    int i = blockIdx.x * 256 + t;
    int v = (i < n) ? counts[i] : 0;
    sm[t] = v;
    __syncthreads();
    for (int off = 1; off < 256; off <<= 1) {
        int u = (t >= off) ? sm[t - off] : 0;
        __syncthreads();
        sm[t] += u;
        __syncthreads();
    }
    int excl = sm[t] - v + boff[blockIdx.x];
    if (i < n) { rs[i] = excl; cursor[i] = excl; }
}

__global__ __launch_bounds__(256) void k_scatter(const int* __restrict__ src,
                                                 const int* __restrict__ dst,
                                                 int* __restrict__ cursor,
                                                 int* __restrict__ csr, int e) {
    int i = blockIdx.x * 256 + threadIdx.x;
    if (i < e) {
        int p = atomicAdd(&cursor[dst[i]], 1);
        csr[p] = src[i];
    }
}

__global__ void k_gbounds(const int* __restrict__ batch, int* __restrict__ gstart,
                          int n, int ng) {
    int g = blockIdx.x * blockDim.x + threadIdx.x;
    if (g > ng) return;
    if (g == ng) { gstart[ng] = n; return; }
    int lo = 0, hi = n;
    while (lo < hi) {
        int mid = (lo + hi) >> 1;
        if (batch[mid] < g) lo = mid + 1; else hi = mid;
    }
    gstart[g] = lo;
}

// ---------------- weight prep: 3 layers, split fp32 W into bf16 hi/lo, frag-major ----
// frag-major per layer (32768 u16): ((nt*8+ks)*64 + l)*8 + j holds
//   Wcat[ks*32+(l>>4)*8+j][nt*16+(l&15)],  Wcat = [Wl; Wr] (256 x 128).

__global__ __launch_bounds__(256) void k_wprep3(
    const float* __restrict__ W1l, const float* __restrict__ W1r,
    const float* __restrict__ W2l, const float* __restrict__ W2r,
    const float* __restrict__ W3l, const float* __restrict__ W3r,
    unsigned short* __restrict__ whi, unsigned short* __restrict__ wlo) {
    int tid = blockIdx.x * 256 + threadIdx.x;   // 0 .. 98303
    if (tid >= 3 * 32768) return;
    int layer = tid >> 15;
    int t = tid & 32767;
    const float* Wl = (layer == 0) ? W1l : ((layer == 1) ? W2l : W3l);
    const float* Wr = (layer == 0) ? W1r : ((layer == 1) ? W2r : W3r);
    int j = t & 7;
    int fp = t >> 3;
    int l = fp & 63;
    int ks = (fp >> 6) & 7;
    int nt = fp >> 9;
    int k = ks * 32 + ((l >> 4) << 3) + j;
    int n = nt * 16 + (l & 15);
    float v = (k < F) ? Wl[k * F + n] : Wr[(k - F) * F + n];
    unsigned short hi = f2bf(v);
    unsigned short lo = f2bf(v - bf2f(hi));
    whi[tid] = hi;
    wlo[tid] = lo;
}

// ---------------- x prep: fp32 -> bf16 hi/lo ----------------

__global__ __launch_bounds__(256) void k_xprep(const float4* __restrict__ x4,
                                               unsigned short* __restrict__ hi,
                                               unsigned short* __restrict__ lo, int n4) {
    int i = blockIdx.x * 256 + threadIdx.x;
    if (i >= n4) return;
    float4 v = x4[i];
    ushort4 h, l;
    h.x = f2bf(v.x); l.x = f2bf(v.x - bf2f(h.x));
    h.y = f2bf(v.y); l.y = f2bf(v.y - bf2f(h.y));
    h.z = f2bf(v.z); l.z = f2bf(v.z - bf2f(h.z));
    h.w = f2bf(v.w); l.w = f2bf(v.w - bf2f(h.w));
    *(ushort4*)&hi[i * 4] = h;
    *(ushort4*)&lo[i * 4] = l;
}

// ---------------- aggregation (bf16 gather): agg[v] = mean_e h[csr[e]] ----------------
// 16 lanes per node (u16x8 = 16B each), 16 nodes per 256-block; fp32 accumulate;
// epilogue splits mean into bf16 hi/lo.

__global__ __launch_bounds__(256) void k_aggm_bf(
    const unsigned short* __restrict__ hbf, const int* __restrict__ rs,
    const int* __restrict__ csr,
    unsigned short* __restrict__ agghi, unsigned short* __restrict__ agglo, int nnodes)
{
    int v = blockIdx.x * 16 + (threadIdx.x >> 4);
    if (v >= nnodes) return;
    int c = threadIdx.x & 15;
    const u16x8* h8 = (const u16x8*)hbf;
    int e0 = rs[v], e1 = rs[v + 1];

    float s0[8] = {}, s1[8] = {}, s2[8] = {}, s3[8] = {};
    int e = e0;
    for (; e + 4 <= e1; e += 4) {
        int a = csr[e], b = csr[e + 1], c2 = csr[e + 2], d = csr[e + 3];
        u16x8 va = h8[a * 16 + c];
        u16x8 vb = h8[b * 16 + c];
        u16x8 vc = h8[c2 * 16 + c];
        u16x8 vd = h8[d * 16 + c];
#pragma unroll
        for (int j = 0; j < 8; j++) {
            s0[j] += bf2f(va[j]);
            s1[j] += bf2f(vb[j]);
            s2[j] += bf2f(vc[j]);
            s3[j] += bf2f(vd[j]);
        }
    }
    for (; e < e1; e++) {
        u16x8 va = h8[csr[e] * 16 + c];
#pragma unroll
        for (int j = 0; j < 8; j++) s0[j] += bf2f(va[j]);
    }
    const float inv = 1.f / (float)max(e1 - e0, 1);
    u16x8 hi8, lo8;
#pragma unroll
    for (int j = 0; j < 8; j++) {
        float m = (s0[j] + s1[j] + s2[j] + s3[j]) * inv;
        unsigned short h = f2bf(m);
        hi8[j] = h;
        lo8[j] = f2bf(m - bf2f(h));
    }
    ((u16x8*)agghi)[v * 16 + c] = hi8;
    ((u16x8*)agglo)[v * 16 + c] = lo8;
}

// ---------------- fused MFMA GEMM: C = relu([Agg|H] @ [Wl;Wr] + bias), bf16 in/out ----
// K = 256; split-bf16 3-pass: Ahi@Whi + Ahi@Wlo + Alo@Whi.
// Block: 256 threads (4 waves), 64 rows x 128 cols. Wave w: col-tiles {2w,2w+1}.
// LDS hi/lo tiles XOR-swizzled at 8-elem grain: idx ^= (row&7)<<3.

__global__ __launch_bounds__(256, 2) void k_gemm_fused(
    const unsigned short* __restrict__ Ahi, const unsigned short* __restrict__ Alo,
    const unsigned short* __restrict__ Bhi, const unsigned short* __restrict__ Blo,
    const unsigned short* __restrict__ whi, const unsigned short* __restrict__ wlo,
    const float* __restrict__ bias,
    unsigned short* __restrict__ Chi, unsigned short* __restrict__ Clo, int nrows)
{
    __shared__ unsigned short ahi[64 * 256];
    __shared__ unsigned short alo[64 * 256];
    const int t = threadIdx.x;
    const int row0 = blockIdx.x * 64;

    // ---- stage 64 rows x 256 k (bf16 copies, no conversion) ----
    {
        const u16x8* A8h = (const u16x8*)Ahi;
        const u16x8* A8l = (const u16x8*)Alo;
        const u16x8* B8h = (const u16x8*)Bhi;
        const u16x8* B8l = (const u16x8*)Blo;
        u16x8 z8 = (u16x8)0;
#pragma unroll
        for (int it = 0; it < 8; it++) {
            int i = t + 256 * it;          // 0..2047
            int row = i >> 5;              // 0..63
            int c8 = i & 31;               // u16x8 chunk within 256 k
            bool ok = (row0 + row) < nrows;
            const u16x8* ph = (c8 < 16) ? A8h : B8h;
            const u16x8* pl = (c8 < 16) ? A8l : B8l;
            int si = (row0 + row) * 16 + (c8 & 15);
            u16x8 vh = ok ? ph[si] : z8;
            u16x8 vl = ok ? pl[si] : z8;
            int didx = row * 256 + ((c8 * 8) ^ ((row & 7) << 3));
            *(u16x8*)&ahi[didx] = vh;
            *(u16x8*)&alo[didx] = vl;
        }
    }
    __syncthreads();

    const int w = t >> 6;
    const int l = t & 63;
    const int lm = l & 15;
    const int lk = l >> 4;
    const bf16x8* whiv = (const bf16x8*)whi;
    const bf16x8* wlov = (const bf16x8*)wlo;

    f32x4 acc[4][2];
#pragma unroll
    for (int rt = 0; rt < 4; rt++)
#pragma unroll
        for (int j = 0; j < 2; j++) acc[rt][j] = (f32x4)(0.f);

    for (int ks = 0; ks < 8; ks++) {
        const int kidx = ks * 32 + lk * 8;
        bf16x8 ah[4], al[4];
#pragma unroll
        for (int rt = 0; rt < 4; rt++) {
            int row = rt * 16 + lm;
            int idx = row * 256 + (kidx ^ ((row & 7) << 3));
            ah[rt] = *(const bf16x8*)&ahi[idx];
            al[rt] = *(const bf16x8*)&alo[idx];
        }
#pragma unroll
        for (int j = 0; j < 2; j++) {
            int nt = 2 * w + j;
            bf16x8 wh = whiv[(nt * 8 + ks) * 64 + l];
            bf16x8 wl = wlov[(nt * 8 + ks) * 64 + l];
#pragma unroll
            for (int rt = 0; rt < 4; rt++) {
                acc[rt][j] = __builtin_amdgcn_mfma_f32_16x16x32_bf16(ah[rt], wh, acc[rt][j], 0, 0, 0);
                acc[rt][j] = __builtin_amdgcn_mfma_f32_16x16x32_bf16(ah[rt], wl, acc[rt][j], 0, 0, 0);
                acc[rt][j] = __builtin_amdgcn_mfma_f32_16x16x32_bf16(al[rt], wh, acc[rt][j], 0, 0, 0);
            }
        }
    }

    // ---- epilogue: + bias, relu, split bf16 hi/lo, store ----
#pragma unroll
    for (int j = 0; j < 2; j++) {
        int col = (2 * w + j) * 16 + lm;
        float bv = bias[col];
#pragma unroll
        for (int rt = 0; rt < 4; rt++) {
#pragma unroll
            for (int r = 0; r < 4; r++) {
                int row = row0 + rt * 16 + lk * 4 + r;
                if (row < nrows) {
                    float v = fmaxf(acc[rt][j][r] + bv, 0.f);
                    unsigned short h = f2bf(v);
                    Chi[(size_t)row * F + col] = h;
                    Clo[(size_t)row * F + col] = f2bf(v - bf2f(h));
                }
            }
        }
    }
}

// ---------------- per-graph mean pool (reads bf16 hi arrays) ----------------

__global__ void k_pool(const unsigned short* __restrict__ tagg,
                       const unsigned short* __restrict__ h3,
                       const int* __restrict__ gstart,
                       float* __restrict__ ps1, float* __restrict__ ps2)
{
    int g = blockIdx.x, c = threadIdx.x;  // 128 threads
    int v0 = gstart[g], v1 = gstart[g + 1];
    float s1 = 0.f, s2 = 0.f;
    for (int v = v0; v < v1; v++) {
        s1 += bf2f(tagg[(size_t)v * F + c]);
        s2 += bf2f(h3[(size_t)v * F + c]);
    }
    float inv = 1.f / (float)max(v1 - v0, 1);
    ps1[g * F + c] = s1 * inv;
    ps2[g * F + c] = s2 * inv;
}

// ---------------- final tiny GEMM ----------------

__global__ void k_final(const float* __restrict__ ps1, const float* __restrict__ ps2,
                        const float* __restrict__ W4l, const float* __restrict__ W4r,
                        const float* __restrict__ b4, float* __restrict__ out, int ngraph)
{
    int g = blockIdx.x * 4 + (threadIdx.x >> 6);
    int lane = threadIdx.x & 63;
    if (g >= ngraph) return;
    int k0 = lane * 2;
    float a0 = ps1[g * F + k0], a1 = ps1[g * F + k0 + 1];
    float c0v = ps2[g * F + k0], c1v = ps2[g * F + k0 + 1];
    float p0 = a0 * W4l[k0 * 2 + 0] + a1 * W4l[(k0 + 1) * 2 + 0] +
               c0v * W4r[k0 * 2 + 0] + c1v * W4r[(k0 + 1) * 2 + 0];
    float p1 = a0 * W4l[k0 * 2 + 1] + a1 * W4l[(k0 + 1) * 2 + 1] +
               c0v * W4r[k0 * 2 + 1] + c1v * W4r[(k0 + 1) * 2 + 1];
#pragma unroll
    for (int off = 32; off > 0; off >>= 1) {
        p0 += __shfl_down(p0, off);
        p1 += __shfl_down(p1, off);
    }
    if (lane == 0) {
        out[g * 2 + 0] = p0 + b4[0];
        out[g * 2 + 1] = p1 + b4[1];
    }
}

// ---------------- launcher ----------------

extern "C" void kernel_launch(void* const* d_in, const int* in_sizes, int n_in,
                              void* d_out, int out_size, void* d_ws, size_t ws_size,
                              hipStream_t stream)
{
    (void)n_in; (void)out_size; (void)ws_size;
    const float* x    = (const float*)d_in[0];
    const int*   ei   = (const int*)d_in[1];
    const int*   batch= (const int*)d_in[2];
    const float* W1l = (const float*)d_in[3];
    const float* W1r = (const float*)d_in[4];
    const float* b1  = (const float*)d_in[5];
    const float* W2l = (const float*)d_in[6];
    const float* W2r = (const float*)d_in[7];
    const float* b2  = (const float*)d_in[8];
    const float* W3l = (const float*)d_in[9];
    const float* W3r = (const float*)d_in[10];
    const float* b3  = (const float*)d_in[11];
    const float* W4l = (const float*)d_in[12];
    const float* W4r = (const float*)d_in[13];
    const float* b4  = (const float*)d_in[14];
    float* out = (float*)d_out;

    const int N = in_sizes[0] / F;   // 50000
    const int E = in_sizes[1] / 2;   // 600000
    const int NG = NGRAPH;
    const int* src = ei;
    const int* dst = ei + E;
    const int NB = (N + 255) / 256;
    const int EB = (E + 255) / 256;

    char* p = (char*)d_ws;
    auto alloc = [&](size_t bytes) {
        char* r = p;
        p += (bytes + 255) & ~(size_t)255;
        return r;
    };
    int* counts  = (int*)alloc((size_t)N * 4);
    int* rs      = (int*)alloc((size_t)(N + 1) * 4);
    int* cursor  = (int*)alloc((size_t)N * 4);
    int* csr     = (int*)alloc((size_t)E * 4);
    int* gstart  = (int*)alloc((size_t)(NG + 1) * 4);
    int* bsum    = (int*)alloc((size_t)NB * 4);
    int* boff    = (int*)alloc((size_t)NB * 4);
    const size_t WSPLIT = 3 * 32768;  // 3 layers x 32768 u16
    unsigned short* wAhi = (unsigned short*)alloc(WSPLIT * 2);
    unsigned short* wAlo = (unsigned short*)alloc(WSPLIT * 2);
    const size_t NF = (size_t)N * F;
    unsigned short* xhi  = (unsigned short*)alloc(NF * 2);  // doubles as h2hi
    unsigned short* xlo  = (unsigned short*)alloc(NF * 2);  // doubles as h2lo
    unsigned short* H0hi = (unsigned short*)alloc(NF * 2);  // h1 / h3
    unsigned short* H0lo = (unsigned short*)alloc(NF * 2);
    unsigned short* Agghi= (unsigned short*)alloc(NF * 2);
    unsigned short* Agglo= (unsigned short*)alloc(NF * 2);
    float* ps1   = (float*)alloc((size_t)NG * F * 4);
    float* ps2   = (float*)alloc((size_t)NG * F * 4);

    // Prep (independent of CSR chain)
    k_wprep3<<<dim3(384), dim3(256), 0, stream>>>(W1l, W1r, W2l, W2r, W3l, W3r, wAhi, wAlo);
    k_xprep<<<dim3((int)(NF / 4 + 255) / 256, 1, 1), dim3(256), 0, stream>>>(
        (const float4*)x, xhi, xlo, (int)(NF / 4));

    // CSR + graph bounds (rebuilt every call; no static state)
    hipMemsetAsync(counts, 0, (size_t)N * 4, stream);
    k_hist<<<dim3(EB), dim3(256), 0, stream>>>(dst, counts, E);
    k_bsum<<<dim3(NB), dim3(256), 0, stream>>>(counts, bsum, N);
    k_scanb<<<dim3(1), dim3(256), 0, stream>>>(bsum, boff, NB, rs, N);
    k_apply<<<dim3(NB), dim3(256), 0, stream>>>(counts, boff, rs, cursor, N);
    k_scatter<<<dim3(EB), dim3(256), 0, stream>>>(src, dst, cursor, csr, E);
    k_gbounds<<<dim3((NG + 256) / 256), dim3(256), 0, stream>>>(batch, gstart, N, NG);

    const int gemmgrid = (N + 63) / 64;
    const int agggrid  = (N + 15) / 16;

    // Layer 1: Agg = mean(x_nbr); h1 = relu(Agg@W1l + x@W1r + b1)  -> H0
    k_aggm_bf<<<dim3(agggrid), dim3(256), 0, stream>>>(xhi, rs, csr, Agghi, Agglo, N);
    k_gemm_fused<<<dim3(gemmgrid), dim3(256), 0, stream>>>(
        Agghi, Agglo, xhi, xlo, wAhi + 0 * 32768, wAlo + 0 * 32768, b1, H0hi, H0lo, N);
    // Layer 2: h2 = relu(...)  -> xhi/xlo (x dead after layer 1)
    k_aggm_bf<<<dim3(agggrid), dim3(256), 0, stream>>>(H0hi, rs, csr, Agghi, Agglo, N);
    k_gemm_fused<<<dim3(gemmgrid), dim3(256), 0, stream>>>(
        Agghi, Agglo, H0hi, H0lo, wAhi + 1 * 32768, wAlo + 1 * 32768, b2, xhi, xlo, N);
    // Layer 3: h3 = relu(...)  -> H0
    k_aggm_bf<<<dim3(agggrid), dim3(256), 0, stream>>>(xhi, rs, csr, Agghi, Agglo, N);
    k_gemm_fused<<<dim3(gemmgrid), dim3(256), 0, stream>>>(
        Agghi, Agglo, xhi, xlo, wAhi + 2 * 32768, wAlo + 2 * 32768, b3, H0hi, H0lo, N);
    // Layer 4 (pooled): Agg = mean(h3_nbr); pool; tiny GEMM
    k_aggm_bf<<<dim3(agggrid), dim3(256), 0, stream>>>(H0hi, rs, csr, Agghi, Agglo, N);
    k_pool<<<dim3(NG), dim3(F), 0, stream>>>(Agghi, H0hi, gstart, ps1, ps2);
    k_final<<<dim3(NG / 4), dim3(256), 0, stream>>>(ps1, ps2, W4l, W4r, b4, out, NG);
}